// Round 3
// baseline (416.651 us; speedup 1.0000x reference)
//
#include <hip/hip_runtime.h>
#include <hip/hip_bf16.h>

#define B_   4
#define S_   2048
#define E_   512
#define H_   8
#define D_   64
#define FFN_ 2304
#define M_   (B_*S_)   // 8192

typedef __attribute__((ext_vector_type(8))) short short8;
typedef __attribute__((ext_vector_type(4))) float f32x4;

__device__ __forceinline__ ushort f2bs(float f) {
  union { __hip_bfloat16 h; ushort u; } c; c.h = __float2bfloat16(f); return c.u;
}
__device__ __forceinline__ float bs2f(ushort u) {
  union { ushort u; __hip_bfloat16 h; } c; c.u = u; return __bfloat162float(c.h);
}
__device__ __forceinline__ f32x4 mfma16(short8 a, short8 b, f32x4 c) {
  return __builtin_amdgcn_mfma_f32_16x16x32_bf16(a, b, c, 0, 0, 0);
}
__device__ __forceinline__ void gload_lds16(const ushort* g, ushort* l) {
  __builtin_amdgcn_global_load_lds(
      (const __attribute__((address_space(1))) unsigned int*)g,
      (__attribute__((address_space(3))) unsigned int*)l, 16, 0, 0);
}

// ---------------- weight fp32 -> bf16 ----------------
__global__ __launch_bounds__(256) void f2b_kernel(const float* __restrict__ src,
                                                  ushort* __restrict__ dst, int n4) {
  int i = blockIdx.x * 256 + threadIdx.x;
  if (i < n4) {
    float4 v = ((const float4*)src)[i];
    ushort4 o;
    o.x = f2bs(v.x); o.y = f2bs(v.y); o.z = f2bs(v.z); o.w = f2bs(v.w);
    ((ushort4*)dst)[i] = o;
  }
}

// ---------------- cos/sin table [S][64] ----------------
__global__ __launch_bounds__(256) void cstab_kernel(float2* __restrict__ tab) {
  int idx = blockIdx.x * 256 + threadIdx.x;   // 0..131071
  int s = idx >> 6, d = idx & 63;
  float freq = powf(10000.f, -(float)(d & 31) * (1.f/32.f));
  float ang = (float)s * freq;
  float sn, cs;
  sincosf(ang, &sn, &cs);
  tab[idx] = make_float2(cs, sn);
}

// ---------------- RMSNorm: fp32 in -> bf16 out ----------------
__global__ __launch_bounds__(256) void rmsnorm_kernel(const float* __restrict__ x,
                                                      const float* __restrict__ w,
                                                      ushort* __restrict__ out) {
  const int row = blockIdx.x * 4 + (threadIdx.x >> 6);
  const int lane = threadIdx.x & 63;
  const float* xr = x + (size_t)row * E_ + lane * 8;
  float4 v0 = *(const float4*)xr;
  float4 v1 = *(const float4*)(xr + 4);
  float ss = v0.x*v0.x + v0.y*v0.y + v0.z*v0.z + v0.w*v0.w
           + v1.x*v1.x + v1.y*v1.y + v1.z*v1.z + v1.w*v1.w;
  #pragma unroll
  for (int m = 1; m < 64; m <<= 1) ss += __shfl_xor(ss, m, 64);
  float r = rsqrtf(ss * (1.f/(float)E_) + 1e-6f);
  const float* wp = w + lane * 8;
  ushort4 o0, o1;
  o0.x = f2bs(v0.x*r*wp[0]); o0.y = f2bs(v0.y*r*wp[1]);
  o0.z = f2bs(v0.z*r*wp[2]); o0.w = f2bs(v0.w*r*wp[3]);
  o1.x = f2bs(v1.x*r*wp[4]); o1.y = f2bs(v1.y*r*wp[5]);
  o1.z = f2bs(v1.z*r*wp[6]); o1.w = f2bs(v1.w*r*wp[7]);
  ushort* o = out + (size_t)row * E_ + lane * 8;
  *(ushort4*)o = o0;
  *(ushort4*)(o + 4) = o1;
}

// ---------------- V transpose: qkv V-slice -> Vg[b][h][d][s] ----------------
__global__ __launch_bounds__(256) void vtrans_kernel(const ushort* __restrict__ qkv,
                                                     ushort* __restrict__ vg) {
  __shared__ ushort Vs[64][72];
  const int s0 = blockIdx.x * 64;
  const int bh = blockIdx.y;
  const int b = bh >> 3, h = bh & 7;
  const int tid = threadIdx.x;
  const int r = tid >> 3, c = (tid & 7) * 8;    // r 0..31, c 0..56
  const size_t base = (size_t)b * S_ * 1536 + 2*E_ + h*64;
  #pragma unroll
  for (int half = 0; half < 2; ++half) {
    int rr = r + half*32;
    const ushort* src = qkv + base + (size_t)(s0 + rr) * 1536 + c;
    *(short8*)&Vs[rr][c ^ (8*((rr>>3)&7))] = *(const short8*)src;
  }
  __syncthreads();
  #pragma unroll
  for (int half = 0; half < 2; ++half) {
    int d = r + half*32;
    short8 o;
    #pragma unroll
    for (int u = 0; u < 8; ++u) {
      int row = c + u;
      o[u] = (short)Vs[row][d ^ (8*((row>>3)&7))];
    }
    *(short8*)(vg + ((size_t)(bh*64 + d))*S_ + s0 + c) = o;
  }
}

// ---------------- causal flash attention: 1 wave / block, no barriers ----------
// grid 2048 = (S/32) x (B*H); each wave owns 32 q-rows, streams KV tiles of 64
// directly from global (L2-resident). Only LDS use: 4.6KB P re-layout (wave-local).
__global__ __launch_bounds__(64) void attn_kernel(const ushort* __restrict__ qkv,
                                                  const ushort* __restrict__ vg,
                                                  ushort* __restrict__ ctx) {
  const int qw = 63 - (int)(blockIdx.x >> 5);   // long diagonals first
  const int bh = blockIdx.x & 31;
  const int b = bh >> 3, h = bh & 7;
  const int lane = threadIdx.x;
  const int l16 = lane & 15, hi = lane >> 4;

  __shared__ ushort Ps[32][72];

  const size_t bbase = (size_t)b * S_ * 1536;
  const int qrow0 = qw * 32;
  const ushort* kbase = qkv + bbase + E_ + h*64;
  const ushort* vbase = vg + (size_t)(bh*64) * S_;

  short8 qf[2][2];
  #pragma unroll
  for (int m = 0; m < 2; ++m) {
    const ushort* qr = qkv + bbase + (size_t)(qrow0 + m*16 + l16) * 1536 + h*64;
    qf[m][0] = *(const short8*)(qr + hi*8);
    qf[m][1] = *(const short8*)(qr + 32 + hi*8);
  }

  f32x4 acc[2][4];
  #pragma unroll
  for (int m = 0; m < 2; ++m)
    #pragma unroll
    for (int d = 0; d < 4; ++d) acc[m][d] = (f32x4){0.f,0.f,0.f,0.f};
  float mrun[2][4], lrun[2][4];
  #pragma unroll
  for (int m = 0; m < 2; ++m)
    #pragma unroll
    for (int j = 0; j < 4; ++j) { mrun[m][j] = -1e30f; lrun[m][j] = 0.f; }

  const int tmax = (qrow0 + 31) >> 6;
  for (int t = 0; t <= tmax; ++t) {
    // ---- K fragments direct from global ----
    short8 kf[4][2];
    #pragma unroll
    for (int s4 = 0; s4 < 4; ++s4) {
      const ushort* kr = kbase + (size_t)(t*64 + s4*16 + l16) * 1536;
      kf[s4][0] = *(const short8*)(kr + hi*8);
      kf[s4][1] = *(const short8*)(kr + 32 + hi*8);
    }
    // ---- QK^T: 16 MFMAs ----
    float scr[2][4][4];
    #pragma unroll
    for (int s4 = 0; s4 < 4; ++s4)
      #pragma unroll
      for (int m = 0; m < 2; ++m) {
        f32x4 a = (f32x4){0.f,0.f,0.f,0.f};
        a = mfma16(qf[m][0], kf[s4][0], a);
        a = mfma16(qf[m][1], kf[s4][1], a);
        #pragma unroll
        for (int j = 0; j < 4; ++j) scr[m][s4][j] = a[j] * 0.125f;
      }
    // ---- V^T fragments (issued early; consumed after softmax) ----
    short8 vf[4][2];
    #pragma unroll
    for (int d = 0; d < 4; ++d) {
      const ushort* vr = vbase + (size_t)(d*16 + l16) * S_ + t*64;
      vf[d][0] = *(const short8*)(vr + hi*8);
      vf[d][1] = *(const short8*)(vr + 32 + hi*8);
    }
    if (t == tmax) {
      #pragma unroll
      for (int m = 0; m < 2; ++m)
        #pragma unroll
        for (int s4 = 0; s4 < 4; ++s4)
          #pragma unroll
          for (int j = 0; j < 4; ++j)
            if (t*64 + s4*16 + l16 > qrow0 + m*16 + hi*4 + j) scr[m][s4][j] = -1e30f;
    }
    // ---- online softmax ----
    #pragma unroll
    for (int m = 0; m < 2; ++m) {
      float mt[4];
      #pragma unroll
      for (int j = 0; j < 4; ++j)
        mt[j] = fmaxf(fmaxf(scr[m][0][j], scr[m][1][j]), fmaxf(scr[m][2][j], scr[m][3][j]));
      #pragma unroll
      for (int msk = 1; msk <= 8; msk <<= 1)
        #pragma unroll
        for (int j = 0; j < 4; ++j) mt[j] = fmaxf(mt[j], __shfl_xor(mt[j], msk, 64));
      float ls[4], alpha[4], pv[4][4];
      #pragma unroll
      for (int j = 0; j < 4; ++j) {
        float mn = fmaxf(mrun[m][j], mt[j]);
        alpha[j] = __expf(mrun[m][j] - mn);
        mrun[m][j] = mn;
        ls[j] = 0.f;
        #pragma unroll
        for (int s4 = 0; s4 < 4; ++s4) { pv[s4][j] = __expf(scr[m][s4][j] - mn); ls[j] += pv[s4][j]; }
      }
      #pragma unroll
      for (int msk = 1; msk <= 8; msk <<= 1)
        #pragma unroll
        for (int j = 0; j < 4; ++j) ls[j] += __shfl_xor(ls[j], msk, 64);
      #pragma unroll
      for (int j = 0; j < 4; ++j) lrun[m][j] = lrun[m][j]*alpha[j] + ls[j];
      #pragma unroll
      for (int d = 0; d < 4; ++d)
        #pragma unroll
        for (int j = 0; j < 4; ++j) acc[m][d][j] *= alpha[j];
      #pragma unroll
      for (int s4 = 0; s4 < 4; ++s4)
        #pragma unroll
        for (int j = 0; j < 4; ++j)
          Ps[m*16 + hi*4 + j][s4*16 + l16] = f2bs(pv[s4][j]);
    }
    // ---- PV: 16 MFMAs (P re-fragmented via wave-local LDS, no barrier) ----
    short8 pf[2][2];
    #pragma unroll
    for (int m = 0; m < 2; ++m) {
      pf[m][0] = *(const short8*)&Ps[m*16 + l16][hi*8];
      pf[m][1] = *(const short8*)&Ps[m*16 + l16][32 + hi*8];
    }
    #pragma unroll
    for (int d = 0; d < 4; ++d)
      #pragma unroll
      for (int m = 0; m < 2; ++m) {
        acc[m][d] = mfma16(pf[m][0], vf[d][0], acc[m][d]);
        acc[m][d] = mfma16(pf[m][1], vf[d][1], acc[m][d]);
      }
  }

  #pragma unroll
  for (int m = 0; m < 2; ++m)
    #pragma unroll
    for (int j = 0; j < 4; ++j) {
      float inv = 1.f / lrun[m][j];
      int srow = qrow0 + m*16 + hi*4 + j;
      #pragma unroll
      for (int d = 0; d < 4; ++d)
        ctx[((size_t)(b * S_ + srow)) * E_ + h*D_ + d*16 + l16] = f2bs(acc[m][d][j] * inv);
    }
}

// ---------------- GEMM: C[M,N] = A[M,K] @ W[N,K]^T (both bf16)
// MODE 0: store bf16 with fused RoPE on cols<1024 (rows are tokens)
// MODE 1: fp32 + residual(aux fp32)   MODE 2: bf16 silu   MODE 3: bf16 acc*aux
template<int MODE>
__global__ __launch_bounds__(256) void gemm_bt(const ushort* __restrict__ A,
                                               const ushort* __restrict__ W,
                                               void* __restrict__ outp,
                                               const void* __restrict__ aux,
                                               const float2* __restrict__ tab,
                                               int M, int N, int K) {
  __shared__ ushort As[128*32];
  __shared__ ushort Bs[128*32];
  const int tid = threadIdx.x;
  const int lane = tid & 63;
  const int w = tid >> 6;
  const int wr = w >> 1, wc = w & 1;
  const int l16 = lane & 15, hi = lane >> 4;
  const int bm = blockIdx.y, bn = blockIdx.x;

  f32x4 acc[4][4];
  #pragma unroll
  for (int m = 0; m < 4; ++m)
    #pragma unroll
    for (int n = 0; n < 4; ++n) acc[m][n] = (f32x4){0.f,0.f,0.f,0.f};

  const int srow = tid >> 2;
  const int scol = (tid & 3) * 8;
  const ushort* ga = A + (size_t)(bm*128 + srow) * K + scol;
  const ushort* gb = W + (size_t)(bn*128 + srow) * K + scol;

  for (int k0 = 0; k0 < K; k0 += 32) {
    gload_lds16(ga + k0,                 &As[tid*8]);
    gload_lds16(ga + k0 + (size_t)64*K,  &As[2048 + tid*8]);
    gload_lds16(gb + k0,                 &Bs[tid*8]);
    gload_lds16(gb + k0 + (size_t)64*K,  &Bs[2048 + tid*8]);
    __syncthreads();
    short8 af[4], bf[4];
    #pragma unroll
    for (int m = 0; m < 4; ++m)
      af[m] = *(const short8*)&As[(wr*64 + m*16 + l16)*32 + hi*8];
    #pragma unroll
    for (int n = 0; n < 4; ++n)
      bf[n] = *(const short8*)&Bs[(wc*64 + n*16 + l16)*32 + hi*8];
    #pragma unroll
    for (int m = 0; m < 4; ++m)
      #pragma unroll
      for (int n = 0; n < 4; ++n)
        acc[m][n] = mfma16(af[m], bf[n], acc[m][n]);
    __syncthreads();
  }
  #pragma unroll
  for (int m = 0; m < 4; ++m)
    #pragma unroll
    for (int n = 0; n < 4; ++n)
      #pragma unroll
      for (int j = 0; j < 4; ++j) {
        int row = bm*128 + wr*64 + m*16 + hi*4 + j;
        int col = bn*128 + wc*64 + n*16 + l16;
        size_t o = (size_t)row * N + col;
        float v = acc[m][n][j];
        if (MODE == 0) {
          float vp = __shfl_xor(v, 1, 64);   // partner element (col^1)
          float outv = v;
          if (col < 1024) {                   // q,k slices get RoPE
            float2 cs = tab[((row & 2047) << 6) + (col & 63)];
            outv = (col & 1) ? (v*cs.x + vp*cs.y) : (v*cs.x - vp*cs.y);
          }
          ((ushort*)outp)[o] = f2bs(outv);
        }
        else if (MODE == 1) ((float*)outp)[o] = v + ((const float*)aux)[o];
        else if (MODE == 2) ((ushort*)outp)[o] = f2bs(v / (1.f + __expf(-v)));
        else                ((ushort*)outp)[o] = f2bs(v * bs2f(((const ushort*)aux)[o]));
      }
}

// ---------------- fused gate/up SwiGLU GEMM: out = silu(A@Wg^T) * (A@Wu^T) ----
__global__ __launch_bounds__(256) void gemm_swiglu(const ushort* __restrict__ A,
                                                   const ushort* __restrict__ Wg,
                                                   const ushort* __restrict__ Wu,
                                                   ushort* __restrict__ outp,
                                                   int M, int N, int K) {
  __shared__ ushort As[128*32];
  __shared__ ushort Bg[128*32];
  __shared__ ushort Bu[128*32];
  const int tid = threadIdx.x;
  const int lane = tid & 63;
  const int w = tid >> 6;
  const int wr = w >> 1, wc = w & 1;
  const int l16 = lane & 15, hi = lane >> 4;
  const int bm = blockIdx.y, bn = blockIdx.x;

  f32x4 accg[4][4], accu[4][4];
  #pragma unroll
  for (int m = 0; m < 4; ++m)
    #pragma unroll
    for (int n = 0; n < 4; ++n) {
      accg[m][n] = (f32x4){0.f,0.f,0.f,0.f};
      accu[m][n] = (f32x4){0.f,0.f,0.f,0.f};
    }

  const int srow = tid >> 2;
  const int scol = (tid & 3) * 8;
  const ushort* ga = A  + (size_t)(bm*128 + srow) * K + scol;
  const ushort* gg = Wg + (size_t)(bn*128 + srow) * K + scol;
  const ushort* gu = Wu + (size_t)(bn*128 + srow) * K + scol;

  for (int k0 = 0; k0 < K; k0 += 32) {
    gload_lds16(ga + k0,                 &As[tid*8]);
    gload_lds16(ga + k0 + (size_t)64*K,  &As[2048 + tid*8]);
    gload_lds16(gg + k0,                 &Bg[tid*8]);
    gload_lds16(gg + k0 + (size_t)64*K,  &Bg[2048 + tid*8]);
    gload_lds16(gu + k0,                 &Bu[tid*8]);
    gload_lds16(gu + k0 + (size_t)64*K,  &Bu[2048 + tid*8]);
    __syncthreads();
    short8 af[4], bfg[4], bfu[4];
    #pragma unroll
    for (int m = 0; m < 4; ++m)
      af[m] = *(const short8*)&As[(wr*64 + m*16 + l16)*32 + hi*8];
    #pragma unroll
    for (int n = 0; n < 4; ++n) {
      bfg[n] = *(const short8*)&Bg[(wc*64 + n*16 + l16)*32 + hi*8];
      bfu[n] = *(const short8*)&Bu[(wc*64 + n*16 + l16)*32 + hi*8];
    }
    #pragma unroll
    for (int m = 0; m < 4; ++m)
      #pragma unroll
      for (int n = 0; n < 4; ++n) {
        accg[m][n] = mfma16(af[m], bfg[n], accg[m][n]);
        accu[m][n] = mfma16(af[m], bfu[n], accu[m][n]);
      }
    __syncthreads();
  }
  #pragma unroll
  for (int m = 0; m < 4; ++m)
    #pragma unroll
    for (int n = 0; n < 4; ++n)
      #pragma unroll
      for (int j = 0; j < 4; ++j) {
        int row = bm*128 + wr*64 + m*16 + hi*4 + j;
        int col = bn*128 + wc*64 + n*16 + l16;
        float g = accg[m][n][j];
        float u = accu[m][n][j];
        outp[(size_t)row * N + col] = f2bs(g / (1.f + __expf(-g)) * u);
      }
}

extern "C" void kernel_launch(void* const* d_in, const int* in_sizes, int n_in,
                              void* d_out, int out_size, void* d_ws, size_t ws_size,
                              hipStream_t stream) {
  const float* x      = (const float*)d_in[0];
  const float* qkv_w  = (const float*)d_in[1];
  const float* out_w  = (const float*)d_in[2];
  const float* n1_w   = (const float*)d_in[3];
  const float* n2_w   = (const float*)d_in[4];
  const float* gate_w = (const float*)d_in[5];
  const float* up_w   = (const float*)d_in[6];
  const float* down_w = (const float*)d_in[7];
  float* outp = (float*)d_out;

  char* ws = (char*)d_ws;
  ushort* wqkv  = (ushort*)ws; ws += (size_t)1536*512*2;
  ushort* wout  = (ushort*)ws; ws += (size_t)512*512*2;
  ushort* wgate = (ushort*)ws; ws += (size_t)2304*512*2;
  ushort* wup   = (ushort*)ws; ws += (size_t)2304*512*2;
  ushort* wdown = (ushort*)ws; ws += (size_t)512*2304*2;
  ushort* h     = (ushort*)ws; ws += (size_t)M_*E_*2;
  ushort* qkv   = (ushort*)ws; ws += (size_t)M_*1536*2;
  ushort* ctx   = (ushort*)ws; ws += (size_t)M_*E_*2;
  ushort* ffn   = (ushort*)ws; ws += (size_t)M_*FFN_*2;
  float2* tab   = (float2*)ws; ws += (size_t)S_*64*8;
  ushort* vgt   = (ushort*)ffn;   // alias: vgt dead before ffn is written

  f2b_kernel<<<768, 256, 0, stream>>>(qkv_w, wqkv, 1536*512/4);
  f2b_kernel<<<256, 256, 0, stream>>>(out_w, wout, 512*512/4);
  f2b_kernel<<<1152, 256, 0, stream>>>(gate_w, wgate, 2304*512/4);
  f2b_kernel<<<1152, 256, 0, stream>>>(up_w, wup, 2304*512/4);
  f2b_kernel<<<1152, 256, 0, stream>>>(down_w, wdown, 512*2304/4);
  cstab_kernel<<<512, 256, 0, stream>>>(tab);

  rmsnorm_kernel<<<M_/4, 256, 0, stream>>>(x, n1_w, h);
  gemm_bt<0><<<dim3(1536/128, M_/128), 256, 0, stream>>>(h, wqkv, qkv, nullptr, tab, M_, 1536, 512);
  vtrans_kernel<<<dim3(S_/64, B_*H_), 256, 0, stream>>>(qkv, vgt);
  attn_kernel<<<2048, 64, 0, stream>>>(qkv, vgt, ctx);
  gemm_bt<1><<<dim3(512/128, M_/128), 256, 0, stream>>>(ctx, wout, outp, x, nullptr, M_, 512, 512);
  rmsnorm_kernel<<<M_/4, 256, 0, stream>>>(outp, n2_w, h);
  gemm_swiglu<<<dim3(2304/128, M_/128), 256, 0, stream>>>(h, wgate, wup, ffn, M_, 2304, 512);
  gemm_bt<1><<<dim3(512/128, M_/128), 256, 0, stream>>>(ffn, wdown, outp, outp, nullptr, M_, 512, 2304);
}

// Round 4
// 373.409 us; speedup vs baseline: 1.1158x; 1.1158x over previous
//
#include <hip/hip_runtime.h>
#include <hip/hip_bf16.h>

#define B_   4
#define S_   2048
#define E_   512
#define H_   8
#define D_   64
#define FFN_ 2304
#define M_   (B_*S_)   // 8192

typedef __attribute__((ext_vector_type(8))) short short8;
typedef __attribute__((ext_vector_type(4))) float f32x4;

__device__ __forceinline__ ushort f2bs(float f) {
  union { __hip_bfloat16 h; ushort u; } c; c.h = __float2bfloat16(f); return c.u;
}
__device__ __forceinline__ float bs2f(ushort u) {
  union { ushort u; __hip_bfloat16 h; } c; c.u = u; return __bfloat162float(c.h);
}
__device__ __forceinline__ f32x4 mfma16(short8 a, short8 b, f32x4 c) {
  return __builtin_amdgcn_mfma_f32_16x16x32_bf16(a, b, c, 0, 0, 0);
}
__device__ __forceinline__ void gload_lds16(const ushort* g, ushort* l) {
  __builtin_amdgcn_global_load_lds(
      (const __attribute__((address_space(1))) unsigned int*)g,
      (__attribute__((address_space(3))) unsigned int*)l, 16, 0, 0);
}

// ---------------- weight fp32 -> bf16 ----------------
__global__ __launch_bounds__(256) void f2b_kernel(const float* __restrict__ src,
                                                  ushort* __restrict__ dst, int n4) {
  int i = blockIdx.x * 256 + threadIdx.x;
  if (i < n4) {
    float4 v = ((const float4*)src)[i];
    ushort4 o;
    o.x = f2bs(v.x); o.y = f2bs(v.y); o.z = f2bs(v.z); o.w = f2bs(v.w);
    ((ushort4*)dst)[i] = o;
  }
}

// ---------------- cos/sin table [S][64] ----------------
__global__ __launch_bounds__(256) void cstab_kernel(float2* __restrict__ tab) {
  int idx = blockIdx.x * 256 + threadIdx.x;   // 0..131071
  int s = idx >> 6, d = idx & 63;
  float freq = powf(10000.f, -(float)(d & 31) * (1.f/32.f));
  float ang = (float)s * freq;
  float sn, cs;
  sincosf(ang, &sn, &cs);
  tab[idx] = make_float2(cs, sn);
}

// ---------------- RMSNorm: fp32 in -> bf16 out ----------------
__global__ __launch_bounds__(256) void rmsnorm_kernel(const float* __restrict__ x,
                                                      const float* __restrict__ w,
                                                      ushort* __restrict__ out) {
  const int row = blockIdx.x * 4 + (threadIdx.x >> 6);
  const int lane = threadIdx.x & 63;
  const float* xr = x + (size_t)row * E_ + lane * 8;
  float4 v0 = *(const float4*)xr;
  float4 v1 = *(const float4*)(xr + 4);
  float ss = v0.x*v0.x + v0.y*v0.y + v0.z*v0.z + v0.w*v0.w
           + v1.x*v1.x + v1.y*v1.y + v1.z*v1.z + v1.w*v1.w;
  #pragma unroll
  for (int m = 1; m < 64; m <<= 1) ss += __shfl_xor(ss, m, 64);
  float r = rsqrtf(ss * (1.f/(float)E_) + 1e-6f);
  const float* wp = w + lane * 8;
  ushort4 o0, o1;
  o0.x = f2bs(v0.x*r*wp[0]); o0.y = f2bs(v0.y*r*wp[1]);
  o0.z = f2bs(v0.z*r*wp[2]); o0.w = f2bs(v0.w*r*wp[3]);
  o1.x = f2bs(v1.x*r*wp[4]); o1.y = f2bs(v1.y*r*wp[5]);
  o1.z = f2bs(v1.z*r*wp[6]); o1.w = f2bs(v1.w*r*wp[7]);
  ushort* o = out + (size_t)row * E_ + lane * 8;
  *(ushort4*)o = o0;
  *(ushort4*)(o + 4) = o1;
}

// ---------------- V transpose: qkv V-slice -> Vg[b][h][d][s] ----------------
__global__ __launch_bounds__(256) void vtrans_kernel(const ushort* __restrict__ qkv,
                                                     ushort* __restrict__ vg) {
  __shared__ ushort Vs[64][72];
  const int s0 = blockIdx.x * 64;
  const int bh = blockIdx.y;
  const int b = bh >> 3, h = bh & 7;
  const int tid = threadIdx.x;
  const int r = tid >> 3, c = (tid & 7) * 8;    // r 0..31, c 0..56
  const size_t base = (size_t)b * S_ * 1536 + 2*E_ + h*64;
  #pragma unroll
  for (int half = 0; half < 2; ++half) {
    int rr = r + half*32;
    const ushort* src = qkv + base + (size_t)(s0 + rr) * 1536 + c;
    *(short8*)&Vs[rr][c ^ (8*((rr>>3)&7))] = *(const short8*)src;
  }
  __syncthreads();
  #pragma unroll
  for (int half = 0; half < 2; ++half) {
    int d = r + half*32;
    short8 o;
    #pragma unroll
    for (int u = 0; u < 8; ++u) {
      int row = c + u;
      o[u] = (short)Vs[row][d ^ (8*((row>>3)&7))];
    }
    *(short8*)(vg + ((size_t)(bh*64 + d))*S_ + s0 + c) = o;
  }
}

// ---------------- causal flash attention: 1 wave / block, no barriers ----------
__global__ __launch_bounds__(64) void attn_kernel(const ushort* __restrict__ qkv,
                                                  const ushort* __restrict__ vg,
                                                  ushort* __restrict__ ctx) {
  const int qw = 63 - (int)(blockIdx.x >> 5);   // long diagonals first
  const int bh = blockIdx.x & 31;
  const int b = bh >> 3, h = bh & 7;
  const int lane = threadIdx.x;
  const int l16 = lane & 15, hi = lane >> 4;

  __shared__ ushort Ps[32][72];

  const size_t bbase = (size_t)b * S_ * 1536;
  const int qrow0 = qw * 32;
  const ushort* kbase = qkv + bbase + E_ + h*64;
  const ushort* vbase = vg + (size_t)(bh*64) * S_;

  short8 qf[2][2];
  #pragma unroll
  for (int m = 0; m < 2; ++m) {
    const ushort* qr = qkv + bbase + (size_t)(qrow0 + m*16 + l16) * 1536 + h*64;
    qf[m][0] = *(const short8*)(qr + hi*8);
    qf[m][1] = *(const short8*)(qr + 32 + hi*8);
  }

  f32x4 acc[2][4];
  #pragma unroll
  for (int m = 0; m < 2; ++m)
    #pragma unroll
    for (int d = 0; d < 4; ++d) acc[m][d] = (f32x4){0.f,0.f,0.f,0.f};
  float mrun[2][4], lrun[2][4];
  #pragma unroll
  for (int m = 0; m < 2; ++m)
    #pragma unroll
    for (int j = 0; j < 4; ++j) { mrun[m][j] = -1e30f; lrun[m][j] = 0.f; }

  const int tmax = (qrow0 + 31) >> 6;
  for (int t = 0; t <= tmax; ++t) {
    short8 kf[4][2];
    #pragma unroll
    for (int s4 = 0; s4 < 4; ++s4) {
      const ushort* kr = kbase + (size_t)(t*64 + s4*16 + l16) * 1536;
      kf[s4][0] = *(const short8*)(kr + hi*8);
      kf[s4][1] = *(const short8*)(kr + 32 + hi*8);
    }
    float scr[2][4][4];
    #pragma unroll
    for (int s4 = 0; s4 < 4; ++s4)
      #pragma unroll
      for (int m = 0; m < 2; ++m) {
        f32x4 a = (f32x4){0.f,0.f,0.f,0.f};
        a = mfma16(qf[m][0], kf[s4][0], a);
        a = mfma16(qf[m][1], kf[s4][1], a);
        #pragma unroll
        for (int j = 0; j < 4; ++j) scr[m][s4][j] = a[j] * 0.125f;
      }
    short8 vf[4][2];
    #pragma unroll
    for (int d = 0; d < 4; ++d) {
      const ushort* vr = vbase + (size_t)(d*16 + l16) * S_ + t*64;
      vf[d][0] = *(const short8*)(vr + hi*8);
      vf[d][1] = *(const short8*)(vr + 32 + hi*8);
    }
    if (t == tmax) {
      #pragma unroll
      for (int m = 0; m < 2; ++m)
        #pragma unroll
        for (int s4 = 0; s4 < 4; ++s4)
          #pragma unroll
          for (int j = 0; j < 4; ++j)
            if (t*64 + s4*16 + l16 > qrow0 + m*16 + hi*4 + j) scr[m][s4][j] = -1e30f;
    }
    #pragma unroll
    for (int m = 0; m < 2; ++m) {
      float mt[4];
      #pragma unroll
      for (int j = 0; j < 4; ++j)
        mt[j] = fmaxf(fmaxf(scr[m][0][j], scr[m][1][j]), fmaxf(scr[m][2][j], scr[m][3][j]));
      #pragma unroll
      for (int msk = 1; msk <= 8; msk <<= 1)
        #pragma unroll
        for (int j = 0; j < 4; ++j) mt[j] = fmaxf(mt[j], __shfl_xor(mt[j], msk, 64));
      float ls[4], alpha[4], pv[4][4];
      #pragma unroll
      for (int j = 0; j < 4; ++j) {
        float mn = fmaxf(mrun[m][j], mt[j]);
        alpha[j] = __expf(mrun[m][j] - mn);
        mrun[m][j] = mn;
        ls[j] = 0.f;
        #pragma unroll
        for (int s4 = 0; s4 < 4; ++s4) { pv[s4][j] = __expf(scr[m][s4][j] - mn); ls[j] += pv[s4][j]; }
      }
      #pragma unroll
      for (int msk = 1; msk <= 8; msk <<= 1)
        #pragma unroll
        for (int j = 0; j < 4; ++j) ls[j] += __shfl_xor(ls[j], msk, 64);
      #pragma unroll
      for (int j = 0; j < 4; ++j) lrun[m][j] = lrun[m][j]*alpha[j] + ls[j];
      #pragma unroll
      for (int d = 0; d < 4; ++d)
        #pragma unroll
        for (int j = 0; j < 4; ++j) acc[m][d][j] *= alpha[j];
      #pragma unroll
      for (int s4 = 0; s4 < 4; ++s4)
        #pragma unroll
        for (int j = 0; j < 4; ++j)
          Ps[m*16 + hi*4 + j][s4*16 + l16] = f2bs(pv[s4][j]);
    }
    short8 pf[2][2];
    #pragma unroll
    for (int m = 0; m < 2; ++m) {
      pf[m][0] = *(const short8*)&Ps[m*16 + l16][hi*8];
      pf[m][1] = *(const short8*)&Ps[m*16 + l16][32 + hi*8];
    }
    #pragma unroll
    for (int d = 0; d < 4; ++d)
      #pragma unroll
      for (int m = 0; m < 2; ++m) {
        acc[m][d] = mfma16(pf[m][0], vf[d][0], acc[m][d]);
        acc[m][d] = mfma16(pf[m][1], vf[d][1], acc[m][d]);
      }
  }

  #pragma unroll
  for (int m = 0; m < 2; ++m)
    #pragma unroll
    for (int j = 0; j < 4; ++j) {
      float inv = 1.f / lrun[m][j];
      int srow = qrow0 + m*16 + hi*4 + j;
      #pragma unroll
      for (int d = 0; d < 4; ++d)
        ctx[((size_t)(b * S_ + srow)) * E_ + h*D_ + d*16 + l16] = f2bs(acc[m][d][j] * inv);
    }
}

// ---------------- double-buffered GEMM: C[M,N] = A[M,K] @ W[N,K]^T ----------
// 128x128 tile, BK=64, 1 barrier/K-step, prefetch overlapped with MFMA.
// LDS XOR-swizzle (col ^= (row&7)*8) applied on BOTH gload source and ds_read.
// MODE 0: bf16 + fused RoPE on cols<1024  MODE 1: fp32 + residual(aux fp32)
// MODE 2: bf16 silu(acc)                  MODE 3: bf16 acc*aux(bf16)
template<int MODE>
__global__ __launch_bounds__(256) void gemm_db(const ushort* __restrict__ A,
                                               const ushort* __restrict__ W,
                                               void* __restrict__ outp,
                                               const void* __restrict__ aux,
                                               const float2* __restrict__ tab,
                                               int M, int N, int K, int nbn) {
  __shared__ ushort As[2][8192];   // [128][64]
  __shared__ ushort Bs[2][8192];
  const int tid = threadIdx.x;
  const int lane = tid & 63;
  const int w = tid >> 6;
  const int wr = w >> 1, wc = w & 1;
  const int l16 = lane & 15, hi = lane >> 4;

  // XCD-aware swizzle: contiguous run of blocks per XCD, bn fastest (A-tile reuse)
  const int nwg = gridDim.x;
  const int wg = blockIdx.x;
  const int swz = (wg & 7) * (nwg >> 3) + (wg >> 3);
  const int bm = swz / nbn, bn = swz % nbn;

  f32x4 acc[4][4];
  #pragma unroll
  for (int m = 0; m < 4; ++m)
    #pragma unroll
    for (int n = 0; n < 4; ++n) acc[m][n] = (f32x4){0.f,0.f,0.f,0.f};

  // staging: 256 thr x 16B = 4KB = 32 rows/issue; 4 issues per 128x64 tile
  const int srow = tid >> 3;                 // 0..31
  const int scol = (tid & 7) * 8;            // 0..56
  const int colx = scol ^ ((srow & 7) * 8);  // pre-swizzled source column
  const ushort* ga = A + (size_t)(bm*128 + srow) * K + colx;
  const ushort* gb = W + (size_t)(bn*128 + srow) * K + colx;
  const int ldst = srow * 64 + scol;         // linear LDS dest (wave-uniform + lane*16B)

  #pragma unroll
  for (int r = 0; r < 4; ++r) {
    gload_lds16(ga + (size_t)r*32*K, &As[0][r*2048 + ldst]);
    gload_lds16(gb + (size_t)r*32*K, &Bs[0][r*2048 + ldst]);
  }
  __syncthreads();

  const int nsteps = K >> 6;
  int cur = 0;
  for (int t = 0; t < nsteps; ++t) {
    if (t + 1 < nsteps) {
      const ushort* ga2 = ga + (t+1)*64;
      const ushort* gb2 = gb + (t+1)*64;
      #pragma unroll
      for (int r = 0; r < 4; ++r) {
        gload_lds16(ga2 + (size_t)r*32*K, &As[cur^1][r*2048 + ldst]);
        gload_lds16(gb2 + (size_t)r*32*K, &Bs[cur^1][r*2048 + ldst]);
      }
    }
    short8 af[4][2], bf[4][2];
    const int xr = (l16 & 7) * 8;
    #pragma unroll
    for (int m = 0; m < 4; ++m) {
      int row = wr*64 + m*16 + l16;
      af[m][0] = *(const short8*)&As[cur][row*64 + ((hi*8) ^ xr)];
      af[m][1] = *(const short8*)&As[cur][row*64 + ((32 + hi*8) ^ xr)];
    }
    #pragma unroll
    for (int n = 0; n < 4; ++n) {
      int row = wc*64 + n*16 + l16;
      bf[n][0] = *(const short8*)&Bs[cur][row*64 + ((hi*8) ^ xr)];
      bf[n][1] = *(const short8*)&Bs[cur][row*64 + ((32 + hi*8) ^ xr)];
    }
    #pragma unroll
    for (int m = 0; m < 4; ++m)
      #pragma unroll
      for (int n = 0; n < 4; ++n) {
        acc[m][n] = mfma16(af[m][0], bf[n][0], acc[m][n]);
        acc[m][n] = mfma16(af[m][1], bf[n][1], acc[m][n]);
      }
    __syncthreads();
    cur ^= 1;
  }

  #pragma unroll
  for (int m = 0; m < 4; ++m)
    #pragma unroll
    for (int n = 0; n < 4; ++n)
      #pragma unroll
      for (int j = 0; j < 4; ++j) {
        int row = bm*128 + wr*64 + m*16 + hi*4 + j;
        int col = bn*128 + wc*64 + n*16 + l16;
        size_t o = (size_t)row * N + col;
        float v = acc[m][n][j];
        if (MODE == 0) {
          float vp = __shfl_xor(v, 1, 64);   // partner element (col^1)
          float outv = v;
          if (col < 1024) {                   // q,k slices get RoPE
            float2 cs = tab[((row & 2047) << 6) + (col & 63)];
            outv = (col & 1) ? (v*cs.x + vp*cs.y) : (v*cs.x - vp*cs.y);
          }
          ((ushort*)outp)[o] = f2bs(outv);
        }
        else if (MODE == 1) ((float*)outp)[o] = v + ((const float*)aux)[o];
        else if (MODE == 2) ((ushort*)outp)[o] = f2bs(v / (1.f + __expf(-v)));
        else                ((ushort*)outp)[o] = f2bs(v * bs2f(((const ushort*)aux)[o]));
      }
}

extern "C" void kernel_launch(void* const* d_in, const int* in_sizes, int n_in,
                              void* d_out, int out_size, void* d_ws, size_t ws_size,
                              hipStream_t stream) {
  const float* x      = (const float*)d_in[0];
  const float* qkv_w  = (const float*)d_in[1];
  const float* out_w  = (const float*)d_in[2];
  const float* n1_w   = (const float*)d_in[3];
  const float* n2_w   = (const float*)d_in[4];
  const float* gate_w = (const float*)d_in[5];
  const float* up_w   = (const float*)d_in[6];
  const float* down_w = (const float*)d_in[7];
  float* outp = (float*)d_out;

  char* ws = (char*)d_ws;
  ushort* wqkv  = (ushort*)ws; ws += (size_t)1536*512*2;
  ushort* wout  = (ushort*)ws; ws += (size_t)512*512*2;
  ushort* wgate = (ushort*)ws; ws += (size_t)2304*512*2;
  ushort* wup   = (ushort*)ws; ws += (size_t)2304*512*2;
  ushort* wdown = (ushort*)ws; ws += (size_t)512*2304*2;
  ushort* h     = (ushort*)ws; ws += (size_t)M_*E_*2;
  ushort* qkv   = (ushort*)ws; ws += (size_t)M_*1536*2;
  ushort* ctx   = (ushort*)ws; ws += (size_t)M_*E_*2;
  ushort* ffn   = (ushort*)ws; ws += (size_t)M_*FFN_*2;
  float2* tab   = (float2*)ws; ws += (size_t)S_*64*8;
  ushort* vgt   = (ushort*)ffn;   // alias: vgt dead before ffn is written

  f2b_kernel<<<768, 256, 0, stream>>>(qkv_w, wqkv, 1536*512/4);
  f2b_kernel<<<256, 256, 0, stream>>>(out_w, wout, 512*512/4);
  f2b_kernel<<<1152, 256, 0, stream>>>(gate_w, wgate, 2304*512/4);
  f2b_kernel<<<1152, 256, 0, stream>>>(up_w, wup, 2304*512/4);
  f2b_kernel<<<1152, 256, 0, stream>>>(down_w, wdown, 512*2304/4);
  cstab_kernel<<<512, 256, 0, stream>>>(tab);

  rmsnorm_kernel<<<M_/4, 256, 0, stream>>>(x, n1_w, h);
  gemm_db<0><<<64*12, 256, 0, stream>>>(h, wqkv, qkv, nullptr, tab, M_, 1536, 512, 12);
  vtrans_kernel<<<dim3(S_/64, B_*H_), 256, 0, stream>>>(qkv, vgt);
  attn_kernel<<<2048, 64, 0, stream>>>(qkv, vgt, ctx);
  gemm_db<1><<<64*4, 256, 0, stream>>>(ctx, wout, outp, x, nullptr, M_, 512, 512, 4);
  rmsnorm_kernel<<<M_/4, 256, 0, stream>>>(outp, n2_w, h);
  gemm_db<2><<<64*18, 256, 0, stream>>>(h, wgate, ffn, nullptr, nullptr, M_, 2304, 512, 18);
  gemm_db<3><<<64*18, 256, 0, stream>>>(h, wup, ffn, ffn, nullptr, M_, 2304, 512, 18);
  gemm_db<1><<<64*4, 256, 0, stream>>>(ffn, wdown, outp, outp, nullptr, M_, 512, 2304, 4);
}